// Round 7
// baseline (756.852 us; speedup 1.0000x reference)
//
#include <hip/hip_runtime.h>
#include <math.h>

#define NB 64
#define NT 512
#define ND 768
#define NK 29
#define L2E 1.4426950408889634f
#define LN2 0.6931471805599453f
#define NEG_BIG -1e30f

typedef __attribute__((ext_vector_type(8))) short short8;
typedef __attribute__((ext_vector_type(4))) float floatx4;

__device__ __forceinline__ short bf16r(float f) {   // round-to-nearest-even
    unsigned u = __float_as_uint(f);
    unsigned r = (u + 0x7FFFu + ((u >> 16) & 1u)) >> 16;
    return (short)r;
}

// ---------------------------------------------------------------------------
// Kernel 0: convert w (29x768 fp32) -> wbf (32x768 bf16, rows 29..31 zero)
// ---------------------------------------------------------------------------
__global__ __launch_bounds__(256) void k_prep(const float* __restrict__ w,
                                              short* __restrict__ wbf)
{
    int i = blockIdx.x * 256 + threadIdx.x;            // 32*768 = 24576
    if (i < 32 * ND) {
        int row = i / ND;
        wbf[i] = (row < NK) ? bf16r(w[i]) : (short)0;
    }
}

// ---------------------------------------------------------------------------
// Kernel 1: emissions via bf16 MFMA (bitwise-proven across R0-R5; unchanged).
// ---------------------------------------------------------------------------
__global__ __launch_bounds__(128) void k_emissions(
    const int* __restrict__ x, const float* __restrict__ emb,
    const short* __restrict__ wbf, const float* __restrict__ bias,
    float* __restrict__ em)
{
    __shared__ float red[2 * 256];                     // wave1 partials
    const int lane = threadIdx.x & 63;
    const int wv = threadIdx.x >> 6;                   // d-half (0/1)
    const int col = lane & 15;                         // m for A, n for B
    const int quad = lane >> 4;                        // k-subrange selector
    const int Mbase = blockIdx.x * 16;
    const int tok = Mbase + col;

    const float* arow = emb + (size_t)x[tok] * ND + wv * 384 + quad * 8;
    const short* brow0 = wbf + (size_t)col * ND + wv * 384 + quad * 8;
    const short* brow1 = brow0 + 16 * ND;

    // issue ALL A loads first: 24 x global_load_dwordx4 in flight
    float4 a[24];
#pragma unroll
    for (int c = 0; c < 12; ++c) {
        a[2 * c]     = *(const float4*)(arow + c * 32);
        a[2 * c + 1] = *(const float4*)(arow + c * 32 + 4);
    }

    floatx4 acc0 = {0.f, 0.f, 0.f, 0.f};
    floatx4 acc1 = {0.f, 0.f, 0.f, 0.f};

    short8 b0 = *(const short8*)(brow0);               // B is L2-hot (45 KB)
    short8 b1 = *(const short8*)(brow1);

#pragma unroll
    for (int c = 0; c < 12; ++c) {
        int c1 = (c + 1 <= 11) ? c + 1 : 11;           // clamped prefetch
        short8 nb0 = *(const short8*)(brow0 + c1 * 32);
        short8 nb1 = *(const short8*)(brow1 + c1 * 32);

        short8 af;
        af[0] = bf16r(a[2 * c].x);     af[1] = bf16r(a[2 * c].y);
        af[2] = bf16r(a[2 * c].z);     af[3] = bf16r(a[2 * c].w);
        af[4] = bf16r(a[2 * c + 1].x); af[5] = bf16r(a[2 * c + 1].y);
        af[6] = bf16r(a[2 * c + 1].z); af[7] = bf16r(a[2 * c + 1].w);

        acc0 = __builtin_amdgcn_mfma_f32_16x16x32_bf16(af, b0, acc0, 0, 0, 0);
        acc1 = __builtin_amdgcn_mfma_f32_16x16x32_bf16(af, b1, acc1, 0, 0, 0);

        b0 = nb0; b1 = nb1;
    }

    // reduce the two d-halves; C/D layout: row = quad*4+reg, col = lane&15
    const int r0 = quad * 4;
    if (wv == 1) {
#pragma unroll
        for (int reg = 0; reg < 4; ++reg) {
            red[(r0 + reg) * 16 + col]       = acc0[reg];
            red[256 + (r0 + reg) * 16 + col] = acc1[reg];
        }
    }
    __syncthreads();
    if (wv == 0) {
        float bs0 = bias[col];
        float bs1 = (col < NK - 16) ? bias[16 + col] : 0.f;
#pragma unroll
        for (int reg = 0; reg < 4; ++reg) {
            int row = r0 + reg;
            float v0 = acc0[reg] + red[row * 16 + col] + bs0;
            em[(size_t)(Mbase + row) * NK + col] = v0;
            if (col < NK - 16) {
                float v1 = acc1[reg] + red[256 + row * 16 + col] + bs1;
                em[(size_t)(Mbase + row) * NK + 16 + col] = v1;
            }
        }
    }
}

// ---------------------------------------------------------------------------
// Kernel 2: fused scans, 256 thr/block, ALL barriers at uniform block scope.
// Blocks 0..63 (CRF): all threads stage emS, 1 barrier, waves 1-3 exit,
//   wave 0 runs the R0-verbatim CRF chain (no further barriers).
// Blocks 64..127 (Viterbi): states live entirely in LDS (Stt, 64 KB) --
//   no global states buffer, no cross-wave global coherence question.
//   Loop per 64-step chunk: {wave0 produces chunk ck into Stt} barrier
//   {waves 1-3 recompute that chunk's backpointers with the R0-VERBATIM
//   strided keep-left tournament, overlapping wave0's next chunk}. bp in
//   LDS; wave 0 then runs the R5-verbatim finals + segmented backtrace.
// ---------------------------------------------------------------------------
__global__ __launch_bounds__(256, 1) void k_scan(
    const float* __restrict__ em, const int* __restrict__ tags,
    const float* __restrict__ st, const float* __restrict__ en,
    const float* __restrict__ tr, float* __restrict__ part,
    float* __restrict__ out)
{
    __shared__ __align__(16) unsigned char smem[82432]; // emS | Stt+sbp+smap
    __shared__ __align__(16) float sA[32];              // CRF state vec
    const int tid = threadIdx.x;

    if (blockIdx.x < NB) {
        // ----------------- CRF forward (verbatim R0 arithmetic) ------------
        const int b = blockIdx.x;
        float* emS = (float*)smem;                     // [512][29] = 59392 B
        {
            const float4* src = (const float4*)(em + (size_t)b * NT * NK);
            float4* dst = (float4*)emS;
            for (int i = tid; i < NT * NK / 4; i += 256) dst[i] = src[i];
        }
        __syncthreads();                               // release emS to wave 0
        if (tid >= 64) return;                         // no barriers after this
        const int lane = tid;
        const int jc = (lane < NK) ? lane : NK - 1;
        const float4* sA4 = (const float4*)sA;

        float EC[32];
#pragma unroll
        for (int i = 0; i < NK; ++i) EC[i] = __expf(tr[i * NK + jc]);
#pragma unroll
        for (int i = NK; i < 32; ++i) EC[i] = 0.f;

        float a0v = __expf(st[jc] + emS[jc]);
        if (lane < 32) sA[lane] = (lane < NK) ? a0v : 0.f;

        int eshift = 5 * (NT - 1);
        float eemc = exp2f(fmaf(emS[NK + jc], L2E, -5.0f));
        float rawn = emS[2 * NK + jc];
        float anew = a0v;

        for (int t = 1; t < NT; ++t) {
            float4 A[8];
#pragma unroll
            for (int ii = 0; ii < 8; ++ii) A[ii] = sA4[ii];   // broadcast reads
            float p0 = 0.f, p1 = 0.f, p2 = 0.f, p3 = 0.f;
#pragma unroll
            for (int ii = 0; ii < 8; ++ii) {                  // pads: +0 exact
                p0 = fmaf(A[ii].x, EC[4 * ii + 0], p0);
                p1 = fmaf(A[ii].y, EC[4 * ii + 1], p1);
                p2 = fmaf(A[ii].z, EC[4 * ii + 2], p2);
                p3 = fmaf(A[ii].w, EC[4 * ii + 3], p3);
            }
            anew = ((p0 + p1) + (p2 + p3)) * eemc;
            // refill (off critical chain)
            eemc = exp2f(fmaf(rawn, L2E, -5.0f));
            int tn = t + 2; tn = tn < NT ? tn : NT - 1;
            rawn = emS[tn * NK + jc];

            if ((t & 15) == 0) {       // exact pow2 renorm via lane-0 probe
                unsigned mb = (unsigned)__builtin_amdgcn_readfirstlane(
                                  __float_as_int(anew));
                int ex = (int)((mb >> 23) & 255u) - 127;
                anew *= __int_as_float((unsigned)(127 - ex) << 23);
                eshift += ex;
            }
            if (lane < 32) sA[lane] = (lane < NK) ? anew : 0.f;
        }
        float val = (lane < NK) ? anew * __expf(en[jc]) : 0.f;
#pragma unroll
        for (int s = 32; s; s >>= 1) val += __shfl_xor(val, s);
        float logZ = logf(val) + (float)eshift * LN2;
        const int* tg = tags + b * NT;
        float p = 0.f;
        for (int t = lane; t < NT; t += 64) {
            int tt = tg[t];
            p += emS[t * NK + tt];
            if (t == 0) p += st[tt];
            else        p += tr[tg[t - 1] * NK + tt];
            if (t == NT - 1) p += en[tt];
        }
#pragma unroll
        for (int s = 32; s; s >>= 1) p += __shfl_xor(p, s);
        if (lane == 0) part[b] = logZ - p;
    } else {
        // ----------------- Viterbi: forward + helper bp + trace ------------
        const int b = blockIdx.x - NB;
        const float* emb_b = em + (size_t)b * NT * NK;
        float* Stt = (float*)smem;                     // [512][32] = 64 KB
        unsigned char* sbp = smem + 65536;             // [511][32] = 16352 B
        unsigned char* smap = smem + 65536 + 16352;    // [16][32]
        const int lane = tid;                          // forward wave (tid<64)
        const int c = tid & 31;
        const int jc = (c < NK) ? c : NK - 1;          // == R0 jc for lanes<32

        // transition column, shared by forward vstep and helper tournament
        float Tc[32];
#pragma unroll
        for (int i = 0; i < NK; ++i) Tc[i] = tr[i * NK + jc];
#pragma unroll
        for (int i = NK; i < 32; ++i) Tc[i] = 0.f;

        float sc = 0.f, e0 = 0.f, e1 = 0.f, e2 = 0.f, e3 = 0.f;
        if (tid < 64) {
            sc = (c < NK && lane < 32) ? (st[jc] + emb_b[jc])
                                       : NEG_BIG;      // lanes>=29: NEG_BIG
            if (lane < NK) sc = st[jc] + emb_b[jc];    // lanes<29 exact
            if (lane < 32) Stt[lane] = sc;             // row 0 (29..31 NEG_BIG)
            e0 = emb_b[1 * NK + jc];
            e1 = emb_b[2 * NK + jc];
            e2 = emb_b[3 * NK + jc];
            e3 = emb_b[4 * NK + jc];
        }

        auto vstep = [&](int t, float emt) {
            const float4* prow = (const float4*)(Stt + (t - 1) * 32);
            float4 q[8];
#pragma unroll
            for (int ii = 0; ii < 8; ++ii) q[ii] = prow[ii]; // broadcast reads
            float v[32];
#pragma unroll
            for (int ii = 0; ii < 8; ++ii) {
                v[4 * ii + 0] = q[ii].x + Tc[4 * ii + 0];
                v[4 * ii + 1] = q[ii].y + Tc[4 * ii + 1];
                v[4 * ii + 2] = q[ii].z + Tc[4 * ii + 2];
                v[4 * ii + 3] = q[ii].w + Tc[4 * ii + 3];
            }
            // exact max via triple-tree (bitwise == tournament value)
            float w0 = fmaxf(fmaxf(v[0], v[1]), v[2]);
            float w1 = fmaxf(fmaxf(v[3], v[4]), v[5]);
            float w2 = fmaxf(fmaxf(v[6], v[7]), v[8]);
            float w3 = fmaxf(fmaxf(v[9], v[10]), v[11]);
            float w4 = fmaxf(fmaxf(v[12], v[13]), v[14]);
            float w5 = fmaxf(fmaxf(v[15], v[16]), v[17]);
            float w6 = fmaxf(fmaxf(v[18], v[19]), v[20]);
            float w7 = fmaxf(fmaxf(v[21], v[22]), v[23]);
            float w8 = fmaxf(fmaxf(v[24], v[25]), v[26]);
            float w9 = fmaxf(fmaxf(v[27], v[28]), v[29]);
            float wa = fmaxf(v[30], v[31]);
            float u0 = fmaxf(fmaxf(w0, w1), w2);
            float u1 = fmaxf(fmaxf(w3, w4), w5);
            float u2 = fmaxf(fmaxf(w6, w7), w8);
            float u3 = fmaxf(w9, wa);
            float m  = fmaxf(fmaxf(fmaxf(u0, u1), u2), u3);

            sc = (lane < NK) ? (m + emt) : NEG_BIG;
            if (lane < 32) Stt[t * 32 + lane] = sc;
        };

        int t = 1;
#pragma unroll 1
        for (int ck = 0; ck < 8; ++ck) {
            if (tid < 64) {
                const int iters = (ck < 7) ? 16 : 15;
#pragma unroll 1
                for (int it = 0; it < iters; ++it) {
                    vstep(t + 0, e0); { int tn = t + 4; tn = tn < NT ? tn : NT - 1; e0 = emb_b[tn * NK + jc]; }
                    vstep(t + 1, e1); { int tn = t + 5; tn = tn < NT ? tn : NT - 1; e1 = emb_b[tn * NK + jc]; }
                    vstep(t + 2, e2); { int tn = t + 6; tn = tn < NT ? tn : NT - 1; e2 = emb_b[tn * NK + jc]; }
                    vstep(t + 3, e3); { int tn = t + 7; tn = tn < NT ? tn : NT - 1; e3 = emb_b[tn * NK + jc]; }
                    t += 4;
                }
                if (ck == 7) { vstep(509, e0); vstep(510, e1); vstep(511, e2); }
            }
            __syncthreads();                           // uniform: chunk ck done
            if (tid >= 64) {
                // helpers: bp rows [64ck, 64ck+63] (<=510), R0-verbatim
                const int sub = (tid >> 5) - 2;        // 0..5 (half-wave id)
#pragma unroll 1
                for (int i = 0; i < 11; ++i) {
                    int rr = 64 * ck + 6 * i + sub;    // state row rr -> bp row rr
                    if (rr < 64 * ck + 64 && rr <= 510) {
                        const float4* row = (const float4*)(Stt + rr * 32);
                        float v[32]; int id[32];
#pragma unroll
                        for (int ii = 0; ii < 8; ++ii) {
                            float4 q = row[ii];        // broadcast per half-wave
                            v[4 * ii + 0] = q.x + Tc[4 * ii + 0];
                            v[4 * ii + 1] = q.y + Tc[4 * ii + 1];
                            v[4 * ii + 2] = q.z + Tc[4 * ii + 2];
                            v[4 * ii + 3] = q.w + Tc[4 * ii + 3];
                        }
#pragma unroll
                        for (int i2 = 0; i2 < 32; ++i2) id[i2] = i2;
                        // R0 strided keep-left tournament (verbatim ties)
#pragma unroll
                        for (int w2 = 16; w2 >= 1; w2 >>= 1)
#pragma unroll
                            for (int i2 = 0; i2 < 16; ++i2) if (i2 < w2) {
                                bool gg = v[i2 + w2] > v[i2];
                                v[i2] = gg ? v[i2 + w2] : v[i2];
                                id[i2] = gg ? id[i2 + w2] : id[i2];
                            }
                        sbp[rr * 32 + c] = (unsigned char)id[0];
                    }
                }
            }
        }
        __syncthreads();                               // uniform: bp complete
        if (tid >= 64) return;

        // ---- finals + segmented backtrace (verbatim R5 k_trace) ----
        float vfin = (lane < NK) ? (sc + en[jc]) : NEG_BIG;
        float M = vfin;
#pragma unroll
        for (int s = 32; s; s >>= 1) M = fmaxf(M, __shfl_xor(M, s));
        unsigned long long mk = __ballot((lane < NK) && vfin == M);
        int last = (int)__builtin_ctzll(mk);

        const int cl = lane & 31;
        const int h = lane >> 5;
        int cur8[8];
#pragma unroll
        for (int rep = 0; rep < 8; ++rep) cur8[rep] = cl;
        for (int off = 0; off < 32; ++off) {
#pragma unroll
            for (int rep = 0; rep < 8; ++rep) {
                int s = 2 * rep + h;
                int hi = (s == 15) ? 511 : 32 * s + 32;
                int r = hi - 1 - off;
                if (r >= 32 * s) cur8[rep] = sbp[r * 32 + cur8[rep]];
            }
        }
#pragma unroll
        for (int rep = 0; rep < 8; ++rep)
            smap[(2 * rep + h) * 32 + cl] = (unsigned char)cur8[rep];

        int myhi = 0, cur = last;
        for (int s = 15; s >= 0; --s) {
            if (lane == s) myhi = cur;
            cur = smap[s * 32 + cur];
        }
        float* op = out + 1 + (size_t)b * NT;
        if (lane == 16) op[NT - 1] = (float)last;
        if (lane < 16) {
            int s = lane;
            int hi = (s == 15) ? 511 : 32 * s + 32;
            int cc = myhi;
            for (int r = hi - 1; r >= 32 * s; --r) {
                cc = sbp[r * 32 + cc];
                op[r] = (float)cc;
            }
        }
    }
}

// ---------------------------------------------------------------------------
// Kernel 3: nll = sum_b (logZ_b - num_b)
// ---------------------------------------------------------------------------
__global__ __launch_bounds__(64) void k_finish(const float* __restrict__ part,
                                               float* __restrict__ out)
{
    float v = part[threadIdx.x];
#pragma unroll
    for (int s = 32; s; s >>= 1) v += __shfl_xor(v, s);
    if (threadIdx.x == 0) out[0] = v;
}

extern "C" void kernel_launch(void* const* d_in, const int* in_sizes, int n_in,
                              void* d_out, int out_size, void* d_ws, size_t ws_size,
                              hipStream_t stream) {
    const int*   x    = (const int*)d_in[0];
    const int*   tags = (const int*)d_in[1];
    const float* emb  = (const float*)d_in[2];
    const float* w    = (const float*)d_in[3];
    const float* bias = (const float*)d_in[4];
    const float* st   = (const float*)d_in[5];
    const float* en   = (const float*)d_in[6];
    const float* tr   = (const float*)d_in[7];
    float* out = (float*)d_out;

    short* wbf  = (short*)d_ws;                              // 48 KB
    float* part = (float*)((char*)d_ws + 49152);             // 256 B
    float* em   = (float*)((char*)d_ws + 65536);             // 3.80 MB

    k_prep<<<96, 256, 0, stream>>>(w, wbf);
    k_emissions<<<2048, 128, 0, stream>>>(x, emb, wbf, bias, em);
    k_scan<<<2 * NB, 256, 0, stream>>>(em, tags, st, en, tr, part, out);
    k_finish<<<1, 64, 0, stream>>>(part, out);
}

// Round 8
// 506.219 us; speedup vs baseline: 1.4951x; 1.4951x over previous
//
#include <hip/hip_runtime.h>
#include <math.h>

#define NB 64
#define NT 512
#define ND 768
#define NK 29
#define L2E 1.4426950408889634f
#define LN2 0.6931471805599453f
#define NEG_BIG -1e30f

typedef __attribute__((ext_vector_type(8))) short short8;
typedef __attribute__((ext_vector_type(4))) float floatx4;

__device__ __forceinline__ short bf16r(float f) {   // round-to-nearest-even
    unsigned u = __float_as_uint(f);
    unsigned r = (u + 0x7FFFu + ((u >> 16) & 1u)) >> 16;
    return (short)r;
}

// ---------------------------------------------------------------------------
// Kernel 0: convert w (29x768 fp32) -> wbf (32x768 bf16, rows 29..31 zero)
// ---------------------------------------------------------------------------
__global__ __launch_bounds__(256) void k_prep(const float* __restrict__ w,
                                              short* __restrict__ wbf)
{
    int i = blockIdx.x * 256 + threadIdx.x;            // 32*768 = 24576
    if (i < 32 * ND) {
        int row = i / ND;
        wbf[i] = (row < NK) ? bf16r(w[i]) : (short)0;
    }
}

// ---------------------------------------------------------------------------
// Kernel 1: emissions via bf16 MFMA. R8: __launch_bounds__(128,2) lifts the
// VGPR cap (2 waves/EU -> up to 256 VGPR) so a[24] (96 VGPRs) stays in
// registers instead of spilling to scratch. Arithmetic unchanged (bitwise).
// ---------------------------------------------------------------------------
__global__ __launch_bounds__(128, 2) void k_emissions(
    const int* __restrict__ x, const float* __restrict__ emb,
    const short* __restrict__ wbf, const float* __restrict__ bias,
    float* __restrict__ em)
{
    __shared__ float red[2 * 256];                     // wave1 partials
    const int lane = threadIdx.x & 63;
    const int wv = threadIdx.x >> 6;                   // d-half (0/1)
    const int col = lane & 15;                         // m for A, n for B
    const int quad = lane >> 4;                        // k-subrange selector
    const int Mbase = blockIdx.x * 16;
    const int tok = Mbase + col;

    const float* arow = emb + (size_t)x[tok] * ND + wv * 384 + quad * 8;
    const short* brow0 = wbf + (size_t)col * ND + wv * 384 + quad * 8;
    const short* brow1 = brow0 + 16 * ND;

    // issue ALL A loads first: 24 x global_load_dwordx4 in flight
    float4 a[24];
#pragma unroll
    for (int c = 0; c < 12; ++c) {
        a[2 * c]     = *(const float4*)(arow + c * 32);
        a[2 * c + 1] = *(const float4*)(arow + c * 32 + 4);
    }

    floatx4 acc0 = {0.f, 0.f, 0.f, 0.f};
    floatx4 acc1 = {0.f, 0.f, 0.f, 0.f};

    short8 b0 = *(const short8*)(brow0);               // B is L2-hot (45 KB)
    short8 b1 = *(const short8*)(brow1);

#pragma unroll
    for (int c = 0; c < 12; ++c) {
        int c1 = (c + 1 <= 11) ? c + 1 : 11;           // clamped prefetch
        short8 nb0 = *(const short8*)(brow0 + c1 * 32);
        short8 nb1 = *(const short8*)(brow1 + c1 * 32);

        short8 af;
        af[0] = bf16r(a[2 * c].x);     af[1] = bf16r(a[2 * c].y);
        af[2] = bf16r(a[2 * c].z);     af[3] = bf16r(a[2 * c].w);
        af[4] = bf16r(a[2 * c + 1].x); af[5] = bf16r(a[2 * c + 1].y);
        af[6] = bf16r(a[2 * c + 1].z); af[7] = bf16r(a[2 * c + 1].w);

        acc0 = __builtin_amdgcn_mfma_f32_16x16x32_bf16(af, b0, acc0, 0, 0, 0);
        acc1 = __builtin_amdgcn_mfma_f32_16x16x32_bf16(af, b1, acc1, 0, 0, 0);

        b0 = nb0; b1 = nb1;
    }

    // reduce the two d-halves; C/D layout: row = quad*4+reg, col = lane&15
    const int r0 = quad * 4;
    if (wv == 1) {
#pragma unroll
        for (int reg = 0; reg < 4; ++reg) {
            red[(r0 + reg) * 16 + col]       = acc0[reg];
            red[256 + (r0 + reg) * 16 + col] = acc1[reg];
        }
    }
    __syncthreads();
    if (wv == 0) {
        float bs0 = bias[col];
        float bs1 = (col < NK - 16) ? bias[16 + col] : 0.f;
#pragma unroll
        for (int reg = 0; reg < 4; ++reg) {
            int row = r0 + reg;
            float v0 = acc0[reg] + red[row * 16 + col] + bs0;
            em[(size_t)(Mbase + row) * NK + col] = v0;
            if (col < NK - 16) {
                float v1 = acc1[reg] + red[256 + row * 16 + col] + bs1;
                em[(size_t)(Mbase + row) * NK + 16 + col] = v1;
            }
        }
    }
}

// ---------------------------------------------------------------------------
// Kernel 2: serial scans — VERBATIM R5 (measured 117 us, absmax-0 chain).
// Blocks 0..63: CRF (verbatim R0). Blocks 64..127: Viterbi forward
// values-only (fmax tree == tournament value bitwise), states -> global.
// ---------------------------------------------------------------------------
__global__ __launch_bounds__(64) void k_scan(
    const float* __restrict__ em, const int* __restrict__ tags,
    const float* __restrict__ st, const float* __restrict__ en,
    const float* __restrict__ tr, float* __restrict__ part,
    float* __restrict__ states)
{
    __shared__ __align__(16) float sA[32];
    __shared__ __align__(16) unsigned char smem[NT * NK * 4];
    const float4* sA4 = (const float4*)sA;
    const int lane = threadIdx.x;
    const int jc = (lane < NK) ? lane : NK - 1;

    if (blockIdx.x < NB) {
        // ----------------- CRF forward (verbatim R0) -----------------------
        const int b = blockIdx.x;
        float* emS = (float*)smem;                     // [512][29]
        {
            const float4* src = (const float4*)(em + (size_t)b * NT * NK);
            float4* dst = (float4*)emS;
            for (int i = lane; i < NT * NK / 4; i += 64) dst[i] = src[i];
        }
        float EC[32];
#pragma unroll
        for (int i = 0; i < NK; ++i) EC[i] = __expf(tr[i * NK + jc]);
#pragma unroll
        for (int i = NK; i < 32; ++i) EC[i] = 0.f;

        float a0v = __expf(st[jc] + emS[jc]);
        if (lane < 32) sA[lane] = (lane < NK) ? a0v : 0.f;

        int eshift = 5 * (NT - 1);
        float eemc = exp2f(fmaf(emS[NK + jc], L2E, -5.0f));
        float rawn = emS[2 * NK + jc];
        float anew = a0v;

        for (int t = 1; t < NT; ++t) {
            float4 A[8];
#pragma unroll
            for (int ii = 0; ii < 8; ++ii) A[ii] = sA4[ii];   // broadcast reads
            float p0 = 0.f, p1 = 0.f, p2 = 0.f, p3 = 0.f;
#pragma unroll
            for (int ii = 0; ii < 8; ++ii) {                  // pads: +0 exact
                p0 = fmaf(A[ii].x, EC[4 * ii + 0], p0);
                p1 = fmaf(A[ii].y, EC[4 * ii + 1], p1);
                p2 = fmaf(A[ii].z, EC[4 * ii + 2], p2);
                p3 = fmaf(A[ii].w, EC[4 * ii + 3], p3);
            }
            anew = ((p0 + p1) + (p2 + p3)) * eemc;
            // refill (off critical chain)
            eemc = exp2f(fmaf(rawn, L2E, -5.0f));
            int tn = t + 2; tn = tn < NT ? tn : NT - 1;
            rawn = emS[tn * NK + jc];

            if ((t & 15) == 0) {       // exact pow2 renorm via lane-0 probe
                unsigned mb = (unsigned)__builtin_amdgcn_readfirstlane(
                                  __float_as_int(anew));
                int ex = (int)((mb >> 23) & 255u) - 127;
                anew *= __int_as_float((unsigned)(127 - ex) << 23);
                eshift += ex;
            }
            if (lane < 32) sA[lane] = (lane < NK) ? anew : 0.f;
        }
        float val = (lane < NK) ? anew * __expf(en[jc]) : 0.f;
#pragma unroll
        for (int s = 32; s; s >>= 1) val += __shfl_xor(val, s);
        float logZ = logf(val) + (float)eshift * LN2;
        const int* tg = tags + b * NT;
        float p = 0.f;
        for (int t = lane; t < NT; t += 64) {
            int tt = tg[t];
            p += emS[t * NK + tt];
            if (t == 0) p += st[tt];
            else        p += tr[tg[t - 1] * NK + tt];
            if (t == NT - 1) p += en[tt];
        }
#pragma unroll
        for (int s = 32; s; s >>= 1) p += __shfl_xor(p, s);
        if (lane == 0) part[b] = logZ - p;
    } else {
        // ------------- Viterbi forward, values-only (no id tracking) -------
        const int b = blockIdx.x - NB;
        const float* emb_b = em + (size_t)b * NT * NK;
        float* stt = states + (size_t)b * NT * 32;     // padded rows

        float Tc[32];
#pragma unroll
        for (int i = 0; i < NK; ++i) Tc[i] = tr[i * NK + jc];
#pragma unroll
        for (int i = NK; i < 32; ++i) Tc[i] = 0.f;

        float sc = (lane < NK) ? (st[jc] + emb_b[jc]) : NEG_BIG;
        if (lane < 32) { sA[lane] = sc; stt[lane] = sc; }  // lanes 29..31: NEG_BIG

        float e0 = emb_b[1 * NK + jc];
        float e1 = emb_b[2 * NK + jc];
        float e2 = emb_b[3 * NK + jc];
        float e3 = emb_b[4 * NK + jc];

        auto vstep = [&](int t, float emt) {
            float4 q[8];
#pragma unroll
            for (int ii = 0; ii < 8; ++ii) q[ii] = sA4[ii];   // broadcast reads
            float v[32];
#pragma unroll
            for (int ii = 0; ii < 8; ++ii) {
                v[4 * ii + 0] = q[ii].x + Tc[4 * ii + 0];
                v[4 * ii + 1] = q[ii].y + Tc[4 * ii + 1];
                v[4 * ii + 2] = q[ii].z + Tc[4 * ii + 2];
                v[4 * ii + 3] = q[ii].w + Tc[4 * ii + 3];
            }
            // exact max via triple-tree (bitwise == tournament value)
            float w0 = fmaxf(fmaxf(v[0], v[1]), v[2]);
            float w1 = fmaxf(fmaxf(v[3], v[4]), v[5]);
            float w2 = fmaxf(fmaxf(v[6], v[7]), v[8]);
            float w3 = fmaxf(fmaxf(v[9], v[10]), v[11]);
            float w4 = fmaxf(fmaxf(v[12], v[13]), v[14]);
            float w5 = fmaxf(fmaxf(v[15], v[16]), v[17]);
            float w6 = fmaxf(fmaxf(v[18], v[19]), v[20]);
            float w7 = fmaxf(fmaxf(v[21], v[22]), v[23]);
            float w8 = fmaxf(fmaxf(v[24], v[25]), v[26]);
            float w9 = fmaxf(fmaxf(v[27], v[28]), v[29]);
            float wa = fmaxf(v[30], v[31]);
            float u0 = fmaxf(fmaxf(w0, w1), w2);
            float u1 = fmaxf(fmaxf(w3, w4), w5);
            float u2 = fmaxf(fmaxf(w6, w7), w8);
            float u3 = fmaxf(w9, wa);
            float m  = fmaxf(fmaxf(fmaxf(u0, u1), u2), u3);

            sc = (lane < NK) ? (m + emt) : NEG_BIG;
            if (lane < 32) { sA[lane] = sc; stt[t * 32 + lane] = sc; }
        };

        int t = 1;
        for (; t + 3 < NT; t += 4) {
            vstep(t + 0, e0); { int tn = t + 4; tn = tn < NT ? tn : NT - 1; e0 = emb_b[tn * NK + jc]; }
            vstep(t + 1, e1); { int tn = t + 5; tn = tn < NT ? tn : NT - 1; e1 = emb_b[tn * NK + jc]; }
            vstep(t + 2, e2); { int tn = t + 6; tn = tn < NT ? tn : NT - 1; e2 = emb_b[tn * NK + jc]; }
            vstep(t + 3, e3); { int tn = t + 7; tn = tn < NT ? tn : NT - 1; e3 = emb_b[tn * NK + jc]; }
        }
        vstep(509, e0); vstep(510, e1); vstep(511, e2);
        // finals + backtrace moved to k_bp/k_trace
    }
}

// ---------------------------------------------------------------------------
// Kernel 2b: backpointer recompute. R8: 512 blocks x 64 THREADS — the one
// shape PROVEN to hold Tc/v/id in registers (R0 k_scan: VGPR=132, no spill;
// the 512/256-thread shapes spilled: VGPR=44, 232/~100 us). 8 slices per
// batch; each wave stages an 8 KB state slice in LDS and computes 64 bp rows
// (2 rows in parallel via the two half-waves) with the R0-VERBATIM strided
// keep-left tournament on bitwise-identical inputs => bp bitwise == R0.
// ---------------------------------------------------------------------------
__global__ __launch_bounds__(64) void k_bp(
    const float* __restrict__ states, const float* __restrict__ tr,
    unsigned char* __restrict__ bpg)
{
    __shared__ __align__(16) float stt[64 * 32];           // 8 KB
    const int b = blockIdx.x >> 3;
    const int sg = blockIdx.x & 7;
    const int base = sg * 64;                              // state rows staged
    const float* S = states + (size_t)b * NT * 32 + (size_t)base * 32;
    const int tid = threadIdx.x;
    const int c = tid & 31;
    const int hw = tid >> 5;                               // half-wave 0/1
    const int jc = (c < NK) ? c : NK - 1;

    float Tc[32];
#pragma unroll
    for (int i = 0; i < NK; ++i) Tc[i] = tr[i * NK + jc];
#pragma unroll
    for (int i = NK; i < 32; ++i) Tc[i] = 0.f;

    {   // stage 64 state rows (512 float4), coalesced
        const float4* src = (const float4*)S;
        float4* dst = (float4*)stt;
#pragma unroll
        for (int i = 0; i < 8; ++i) dst[tid + 64 * i] = src[tid + 64 * i];
    }
    __syncthreads();

    unsigned char* bpb = bpg + (size_t)b * 511 * 32;
#pragma unroll 1
    for (int k = 0; k < 32; ++k) {
        int rl = 2 * k + hw;                               // local state row
        int rr = base + rl;                                // bp row rr
        if (rr <= 510) {
            const float4* row = (const float4*)(stt + rl * 32);
            float v[32]; int id[32];
#pragma unroll
            for (int ii = 0; ii < 8; ++ii) {
                float4 q = row[ii];                        // broadcast / half
                v[4 * ii + 0] = q.x + Tc[4 * ii + 0];
                v[4 * ii + 1] = q.y + Tc[4 * ii + 1];
                v[4 * ii + 2] = q.z + Tc[4 * ii + 2];
                v[4 * ii + 3] = q.w + Tc[4 * ii + 3];
            }
#pragma unroll
            for (int i2 = 0; i2 < 32; ++i2) id[i2] = i2;
            // R0 strided keep-left tournament (verbatim tie semantics)
#pragma unroll
            for (int w2 = 16; w2 >= 1; w2 >>= 1)
#pragma unroll
                for (int i2 = 0; i2 < 16; ++i2) if (i2 < w2) {
                    bool gg = v[i2 + w2] > v[i2];
                    v[i2] = gg ? v[i2 + w2] : v[i2];
                    id[i2] = gg ? id[i2 + w2] : id[i2];
                }
            bpb[(size_t)rr * 32 + c] = (unsigned char)id[0];
        }
    }
}

// ---------------------------------------------------------------------------
// Kernel 2c: finals + segmented backtrace (verbatim R5). 64 blocks x 1 wave.
// ---------------------------------------------------------------------------
__global__ __launch_bounds__(64) void k_trace(
    const unsigned char* __restrict__ bpg, const float* __restrict__ states,
    const float* __restrict__ en, float* __restrict__ out)
{
    __shared__ __align__(16) unsigned char sbp[511 * 32];  // 16 KB
    __shared__ unsigned char smap[16 * 32];
    const int b = blockIdx.x;
    const int lane = threadIdx.x;
    const int jc = (lane < NK) ? lane : NK - 1;

    {   // stage bp (16352 B = 1022 uint4), coalesced
        const uint4* src = (const uint4*)(bpg + (size_t)b * 511 * 32);
        uint4* dst = (uint4*)sbp;
        for (int i = lane; i < 1022; i += 64) dst[i] = src[i];
    }
    __syncthreads();

    const float* fin = states + (size_t)b * NT * 32 + 511 * 32;
    int li = (lane < 32) ? lane : 0;
    float sv = fin[li];
    float vfin = (lane < NK) ? (sv + en[jc]) : NEG_BIG;
    float M = vfin;
#pragma unroll
    for (int s = 32; s; s >>= 1) M = fmaxf(M, __shfl_xor(M, s));
    unsigned long long mk = __ballot((lane < NK) && vfin == M);
    int last = (int)__builtin_ctzll(mk);

    const int cl = lane & 31;
    const int h = lane >> 5;
    int cur8[8];
#pragma unroll
    for (int rep = 0; rep < 8; ++rep) cur8[rep] = cl;
    for (int off = 0; off < 32; ++off) {
#pragma unroll
        for (int rep = 0; rep < 8; ++rep) {
            int s = 2 * rep + h;
            int hi = (s == 15) ? 511 : 32 * s + 32;
            int r = hi - 1 - off;
            if (r >= 32 * s) cur8[rep] = sbp[r * 32 + cur8[rep]];
        }
    }
#pragma unroll
    for (int rep = 0; rep < 8; ++rep)
        smap[(2 * rep + h) * 32 + cl] = (unsigned char)cur8[rep];

    int myhi = 0, cur = last;
    for (int s = 15; s >= 0; --s) {
        if (lane == s) myhi = cur;
        cur = smap[s * 32 + cur];
    }
    float* op = out + 1 + (size_t)b * NT;
    if (lane == 16) op[NT - 1] = (float)last;
    if (lane < 16) {
        int s = lane;
        int hi = (s == 15) ? 511 : 32 * s + 32;
        int cc = myhi;
        for (int r = hi - 1; r >= 32 * s; --r) {
            cc = sbp[r * 32 + cc];
            op[r] = (float)cc;
        }
    }
}

// ---------------------------------------------------------------------------
// Kernel 3: nll = sum_b (logZ_b - num_b)
// ---------------------------------------------------------------------------
__global__ __launch_bounds__(64) void k_finish(const float* __restrict__ part,
                                               float* __restrict__ out)
{
    float v = part[threadIdx.x];
#pragma unroll
    for (int s = 32; s; s >>= 1) v += __shfl_xor(v, s);
    if (threadIdx.x == 0) out[0] = v;
}

extern "C" void kernel_launch(void* const* d_in, const int* in_sizes, int n_in,
                              void* d_out, int out_size, void* d_ws, size_t ws_size,
                              hipStream_t stream) {
    const int*   x    = (const int*)d_in[0];
    const int*   tags = (const int*)d_in[1];
    const float* emb  = (const float*)d_in[2];
    const float* w    = (const float*)d_in[3];
    const float* bias = (const float*)d_in[4];
    const float* st   = (const float*)d_in[5];
    const float* en   = (const float*)d_in[6];
    const float* tr   = (const float*)d_in[7];
    float* out = (float*)d_out;

    short* wbf    = (short*)d_ws;                            // 48 KB
    float* part   = (float*)((char*)d_ws + 49152);           // 256 B
    float* em     = (float*)((char*)d_ws + 65536);           // 3.80 MB
    float* states = (float*)((char*)d_ws + 3932160);         // 4.19 MB (ws ~8.2 MB)
    // bp aliases em: em is dead after k_scan completes (stream-ordered)
    unsigned char* bp = (unsigned char*)((char*)d_ws + 65536);

    k_prep<<<96, 256, 0, stream>>>(w, wbf);
    k_emissions<<<2048, 128, 0, stream>>>(x, emb, wbf, bias, em);
    k_scan<<<2 * NB, 64, 0, stream>>>(em, tags, st, en, tr, part, states);
    k_bp<<<8 * NB, 64, 0, stream>>>(states, tr, bp);
    k_trace<<<NB, 64, 0, stream>>>(bp, states, en, out);
    k_finish<<<1, 64, 0, stream>>>(part, out);
}

// Round 9
// 314.808 us; speedup vs baseline: 2.4042x; 1.6080x over previous
//
#include <hip/hip_runtime.h>
#include <math.h>

#define NB 64
#define NT 512
#define ND 768
#define NK 29
#define L2E 1.4426950408889634f
#define LN2 0.6931471805599453f
#define NEG_BIG -1e30f

typedef __attribute__((ext_vector_type(8))) short short8;
typedef __attribute__((ext_vector_type(4))) float floatx4;

__device__ __forceinline__ short bf16r(float f) {   // round-to-nearest-even
    unsigned u = __float_as_uint(f);
    unsigned r = (u + 0x7FFFu + ((u >> 16) & 1u)) >> 16;
    return (short)r;
}

// ---------------------------------------------------------------------------
// Kernel 0: convert w (29x768 fp32) -> wbf (32x768 bf16, rows 29..31 zero)
// ---------------------------------------------------------------------------
__global__ __launch_bounds__(256) void k_prep(const float* __restrict__ w,
                                              short* __restrict__ wbf)
{
    int i = blockIdx.x * 256 + threadIdx.x;            // 32*768 = 24576
    if (i < 32 * ND) {
        int row = i / ND;
        wbf[i] = (row < NK) ? bf16r(w[i]) : (short)0;
    }
}

// ---------------------------------------------------------------------------
// Kernel 1: emissions via bf16 MFMA (bitwise-proven; unchanged from R8).
// Cross-round evidence: ~150us regardless of load structure / launch bounds
// -> gather-BW/latency bound. Counters land next round once k_bp shrinks.
// ---------------------------------------------------------------------------
__global__ __launch_bounds__(128, 2) void k_emissions(
    const int* __restrict__ x, const float* __restrict__ emb,
    const short* __restrict__ wbf, const float* __restrict__ bias,
    float* __restrict__ em)
{
    __shared__ float red[2 * 256];                     // wave1 partials
    const int lane = threadIdx.x & 63;
    const int wv = threadIdx.x >> 6;                   // d-half (0/1)
    const int col = lane & 15;                         // m for A, n for B
    const int quad = lane >> 4;                        // k-subrange selector
    const int Mbase = blockIdx.x * 16;
    const int tok = Mbase + col;

    const float* arow = emb + (size_t)x[tok] * ND + wv * 384 + quad * 8;
    const short* brow0 = wbf + (size_t)col * ND + wv * 384 + quad * 8;
    const short* brow1 = brow0 + 16 * ND;

    // issue ALL A loads first: 24 x global_load_dwordx4 in flight
    float4 a[24];
#pragma unroll
    for (int c = 0; c < 12; ++c) {
        a[2 * c]     = *(const float4*)(arow + c * 32);
        a[2 * c + 1] = *(const float4*)(arow + c * 32 + 4);
    }

    floatx4 acc0 = {0.f, 0.f, 0.f, 0.f};
    floatx4 acc1 = {0.f, 0.f, 0.f, 0.f};

    short8 b0 = *(const short8*)(brow0);               // B is L2-hot (45 KB)
    short8 b1 = *(const short8*)(brow1);

#pragma unroll
    for (int c = 0; c < 12; ++c) {
        int c1 = (c + 1 <= 11) ? c + 1 : 11;           // clamped prefetch
        short8 nb0 = *(const short8*)(brow0 + c1 * 32);
        short8 nb1 = *(const short8*)(brow1 + c1 * 32);

        short8 af;
        af[0] = bf16r(a[2 * c].x);     af[1] = bf16r(a[2 * c].y);
        af[2] = bf16r(a[2 * c].z);     af[3] = bf16r(a[2 * c].w);
        af[4] = bf16r(a[2 * c + 1].x); af[5] = bf16r(a[2 * c + 1].y);
        af[6] = bf16r(a[2 * c + 1].z); af[7] = bf16r(a[2 * c + 1].w);

        acc0 = __builtin_amdgcn_mfma_f32_16x16x32_bf16(af, b0, acc0, 0, 0, 0);
        acc1 = __builtin_amdgcn_mfma_f32_16x16x32_bf16(af, b1, acc1, 0, 0, 0);

        b0 = nb0; b1 = nb1;
    }

    // reduce the two d-halves; C/D layout: row = quad*4+reg, col = lane&15
    const int r0 = quad * 4;
    if (wv == 1) {
#pragma unroll
        for (int reg = 0; reg < 4; ++reg) {
            red[(r0 + reg) * 16 + col]       = acc0[reg];
            red[256 + (r0 + reg) * 16 + col] = acc1[reg];
        }
    }
    __syncthreads();
    if (wv == 0) {
        float bs0 = bias[col];
        float bs1 = (col < NK - 16) ? bias[16 + col] : 0.f;
#pragma unroll
        for (int reg = 0; reg < 4; ++reg) {
            int row = r0 + reg;
            float v0 = acc0[reg] + red[row * 16 + col] + bs0;
            em[(size_t)(Mbase + row) * NK + col] = v0;
            if (col < NK - 16) {
                float v1 = acc1[reg] + red[256 + row * 16 + col] + bs1;
                em[(size_t)(Mbase + row) * NK + 16 + col] = v1;
            }
        }
    }
}

// ---------------------------------------------------------------------------
// Kernel 2: serial scans — VERBATIM R5 (measured 117 us, absmax-0 chain).
// ---------------------------------------------------------------------------
__global__ __launch_bounds__(64) void k_scan(
    const float* __restrict__ em, const int* __restrict__ tags,
    const float* __restrict__ st, const float* __restrict__ en,
    const float* __restrict__ tr, float* __restrict__ part,
    float* __restrict__ states)
{
    __shared__ __align__(16) float sA[32];
    __shared__ __align__(16) unsigned char smem[NT * NK * 4];
    const float4* sA4 = (const float4*)sA;
    const int lane = threadIdx.x;
    const int jc = (lane < NK) ? lane : NK - 1;

    if (blockIdx.x < NB) {
        // ----------------- CRF forward (verbatim R0) -----------------------
        const int b = blockIdx.x;
        float* emS = (float*)smem;                     // [512][29]
        {
            const float4* src = (const float4*)(em + (size_t)b * NT * NK);
            float4* dst = (float4*)emS;
            for (int i = lane; i < NT * NK / 4; i += 64) dst[i] = src[i];
        }
        float EC[32];
#pragma unroll
        for (int i = 0; i < NK; ++i) EC[i] = __expf(tr[i * NK + jc]);
#pragma unroll
        for (int i = NK; i < 32; ++i) EC[i] = 0.f;

        float a0v = __expf(st[jc] + emS[jc]);
        if (lane < 32) sA[lane] = (lane < NK) ? a0v : 0.f;

        int eshift = 5 * (NT - 1);
        float eemc = exp2f(fmaf(emS[NK + jc], L2E, -5.0f));
        float rawn = emS[2 * NK + jc];
        float anew = a0v;

        for (int t = 1; t < NT; ++t) {
            float4 A[8];
#pragma unroll
            for (int ii = 0; ii < 8; ++ii) A[ii] = sA4[ii];   // broadcast reads
            float p0 = 0.f, p1 = 0.f, p2 = 0.f, p3 = 0.f;
#pragma unroll
            for (int ii = 0; ii < 8; ++ii) {                  // pads: +0 exact
                p0 = fmaf(A[ii].x, EC[4 * ii + 0], p0);
                p1 = fmaf(A[ii].y, EC[4 * ii + 1], p1);
                p2 = fmaf(A[ii].z, EC[4 * ii + 2], p2);
                p3 = fmaf(A[ii].w, EC[4 * ii + 3], p3);
            }
            anew = ((p0 + p1) + (p2 + p3)) * eemc;
            // refill (off critical chain)
            eemc = exp2f(fmaf(rawn, L2E, -5.0f));
            int tn = t + 2; tn = tn < NT ? tn : NT - 1;
            rawn = emS[tn * NK + jc];

            if ((t & 15) == 0) {       // exact pow2 renorm via lane-0 probe
                unsigned mb = (unsigned)__builtin_amdgcn_readfirstlane(
                                  __float_as_int(anew));
                int ex = (int)((mb >> 23) & 255u) - 127;
                anew *= __int_as_float((unsigned)(127 - ex) << 23);
                eshift += ex;
            }
            if (lane < 32) sA[lane] = (lane < NK) ? anew : 0.f;
        }
        float val = (lane < NK) ? anew * __expf(en[jc]) : 0.f;
#pragma unroll
        for (int s = 32; s; s >>= 1) val += __shfl_xor(val, s);
        float logZ = logf(val) + (float)eshift * LN2;
        const int* tg = tags + b * NT;
        float p = 0.f;
        for (int t = lane; t < NT; t += 64) {
            int tt = tg[t];
            p += emS[t * NK + tt];
            if (t == 0) p += st[tt];
            else        p += tr[tg[t - 1] * NK + tt];
            if (t == NT - 1) p += en[tt];
        }
#pragma unroll
        for (int s = 32; s; s >>= 1) p += __shfl_xor(p, s);
        if (lane == 0) part[b] = logZ - p;
    } else {
        // ------------- Viterbi forward, values-only (no id tracking) -------
        const int b = blockIdx.x - NB;
        const float* emb_b = em + (size_t)b * NT * NK;
        float* stt = states + (size_t)b * NT * 32;     // padded rows

        float Tc[32];
#pragma unroll
        for (int i = 0; i < NK; ++i) Tc[i] = tr[i * NK + jc];
#pragma unroll
        for (int i = NK; i < 32; ++i) Tc[i] = 0.f;

        float sc = (lane < NK) ? (st[jc] + emb_b[jc]) : NEG_BIG;
        if (lane < 32) { sA[lane] = sc; stt[lane] = sc; }  // lanes 29..31: NEG_BIG

        float e0 = emb_b[1 * NK + jc];
        float e1 = emb_b[2 * NK + jc];
        float e2 = emb_b[3 * NK + jc];
        float e3 = emb_b[4 * NK + jc];

        auto vstep = [&](int t, float emt) {
            float4 q[8];
#pragma unroll
            for (int ii = 0; ii < 8; ++ii) q[ii] = sA4[ii];   // broadcast reads
            float v[32];
#pragma unroll
            for (int ii = 0; ii < 8; ++ii) {
                v[4 * ii + 0] = q[ii].x + Tc[4 * ii + 0];
                v[4 * ii + 1] = q[ii].y + Tc[4 * ii + 1];
                v[4 * ii + 2] = q[ii].z + Tc[4 * ii + 2];
                v[4 * ii + 3] = q[ii].w + Tc[4 * ii + 3];
            }
            // exact max via triple-tree (bitwise == tournament value)
            float w0 = fmaxf(fmaxf(v[0], v[1]), v[2]);
            float w1 = fmaxf(fmaxf(v[3], v[4]), v[5]);
            float w2 = fmaxf(fmaxf(v[6], v[7]), v[8]);
            float w3 = fmaxf(fmaxf(v[9], v[10]), v[11]);
            float w4 = fmaxf(fmaxf(v[12], v[13]), v[14]);
            float w5 = fmaxf(fmaxf(v[15], v[16]), v[17]);
            float w6 = fmaxf(fmaxf(v[18], v[19]), v[20]);
            float w7 = fmaxf(fmaxf(v[21], v[22]), v[23]);
            float w8 = fmaxf(fmaxf(v[24], v[25]), v[26]);
            float w9 = fmaxf(fmaxf(v[27], v[28]), v[29]);
            float wa = fmaxf(v[30], v[31]);
            float u0 = fmaxf(fmaxf(w0, w1), w2);
            float u1 = fmaxf(fmaxf(w3, w4), w5);
            float u2 = fmaxf(fmaxf(w6, w7), w8);
            float u3 = fmaxf(w9, wa);
            float m  = fmaxf(fmaxf(fmaxf(u0, u1), u2), u3);

            sc = (lane < NK) ? (m + emt) : NEG_BIG;
            if (lane < 32) { sA[lane] = sc; stt[t * 32 + lane] = sc; }
        };

        int t = 1;
        for (; t + 3 < NT; t += 4) {
            vstep(t + 0, e0); { int tn = t + 4; tn = tn < NT ? tn : NT - 1; e0 = emb_b[tn * NK + jc]; }
            vstep(t + 1, e1); { int tn = t + 5; tn = tn < NT ? tn : NT - 1; e1 = emb_b[tn * NK + jc]; }
            vstep(t + 2, e2); { int tn = t + 6; tn = tn < NT ? tn : NT - 1; e2 = emb_b[tn * NK + jc]; }
            vstep(t + 3, e3); { int tn = t + 7; tn = tn < NT ? tn : NT - 1; e3 = emb_b[tn * NK + jc]; }
        }
        vstep(509, e0); vstep(510, e1); vstep(511, e2);
        // finals + backtrace moved to k_bp/k_trace
    }
}

// ---------------------------------------------------------------------------
// Kernel 2b: backpointer recompute — STRAIGHT-LINE, NO ARRAYS. R4/R5/R8 all
// spilled (VGPR=44) because the compiler left the tournament's variable-
// stride array indices un-unrolled -> scratch (rule #20). Named scalars +
// explicit fmax tree + descending first-max select cannot spill. Value max
// is exact (== tournament value); index = smallest i attaining it =
// np.argmax first-max. bp written to global (aliases dead em buffer).
// ---------------------------------------------------------------------------
__global__ __launch_bounds__(64) void k_bp(
    const float* __restrict__ states, const float* __restrict__ tr,
    unsigned char* __restrict__ bpg)
{
    __shared__ __align__(16) float stt[64 * 32];           // 8 KB
    const int b = blockIdx.x >> 3;
    const int sg = blockIdx.x & 7;
    const int base = sg * 64;                              // state rows staged
    const float* S = states + (size_t)b * NT * 32 + (size_t)base * 32;
    const int tid = threadIdx.x;
    const int c = tid & 31;
    const int hw = tid >> 5;                               // half-wave 0/1
    const int jc = (c < NK) ? c : NK - 1;

    float Tc[32];                                          // static idx only
#pragma unroll
    for (int i = 0; i < NK; ++i) Tc[i] = tr[i * NK + jc];
#pragma unroll
    for (int i = NK; i < 32; ++i) Tc[i] = 0.f;

    {   // stage 64 state rows (512 float4), coalesced
        const float4* src = (const float4*)S;
        float4* dst = (float4*)stt;
#pragma unroll
        for (int i = 0; i < 8; ++i) dst[tid + 64 * i] = src[tid + 64 * i];
    }
    __syncthreads();

    unsigned char* bpb = bpg + (size_t)b * 511 * 32;
#pragma unroll 1
    for (int k = 0; k < 32; ++k) {
        int rl = 2 * k + hw;                               // local state row
        int rr = base + rl;                                // bp row rr
        if (rr <= 510) {
            const float4* row = (const float4*)(stt + rl * 32);
            float4 q0 = row[0], q1 = row[1], q2 = row[2], q3 = row[3];
            float4 q4 = row[4], q5 = row[5], q6 = row[6], q7 = row[7];
            float v0  = q0.x + Tc[0],  v1  = q0.y + Tc[1];
            float v2  = q0.z + Tc[2],  v3  = q0.w + Tc[3];
            float v4  = q1.x + Tc[4],  v5  = q1.y + Tc[5];
            float v6  = q1.z + Tc[6],  v7  = q1.w + Tc[7];
            float v8  = q2.x + Tc[8],  v9  = q2.y + Tc[9];
            float v10 = q2.z + Tc[10], v11 = q2.w + Tc[11];
            float v12 = q3.x + Tc[12], v13 = q3.y + Tc[13];
            float v14 = q3.z + Tc[14], v15 = q3.w + Tc[15];
            float v16 = q4.x + Tc[16], v17 = q4.y + Tc[17];
            float v18 = q4.z + Tc[18], v19 = q4.w + Tc[19];
            float v20 = q5.x + Tc[20], v21 = q5.y + Tc[21];
            float v22 = q5.z + Tc[22], v23 = q5.w + Tc[23];
            float v24 = q6.x + Tc[24], v25 = q6.y + Tc[25];
            float v26 = q6.z + Tc[26], v27 = q6.w + Tc[27];
            float v28 = q7.x + Tc[28], v29 = q7.y + Tc[29];
            float v30 = q7.z + Tc[30], v31 = q7.w + Tc[31];
            // exact max (any tree): 31 fmax
            float m0 = fmaxf(v0, v1),   m1 = fmaxf(v2, v3);
            float m2 = fmaxf(v4, v5),   m3 = fmaxf(v6, v7);
            float m4 = fmaxf(v8, v9),   m5 = fmaxf(v10, v11);
            float m6 = fmaxf(v12, v13), m7 = fmaxf(v14, v15);
            float m8 = fmaxf(v16, v17), m9 = fmaxf(v18, v19);
            float ma = fmaxf(v20, v21), mb = fmaxf(v22, v23);
            float mc = fmaxf(v24, v25), md = fmaxf(v26, v27);
            float me = fmaxf(v28, v29), mf = fmaxf(v30, v31);
            float n0 = fmaxf(m0, m1), n1 = fmaxf(m2, m3);
            float n2 = fmaxf(m4, m5), n3 = fmaxf(m6, m7);
            float n4 = fmaxf(m8, m9), n5 = fmaxf(ma, mb);
            float n6 = fmaxf(mc, md), n7 = fmaxf(me, mf);
            float o0 = fmaxf(n0, n1), o1 = fmaxf(n2, n3);
            float o2 = fmaxf(n4, n5), o3 = fmaxf(n6, n7);
            float m  = fmaxf(fmaxf(o0, o1), fmaxf(o2, o3));
            // first-max index: descending priority chain (ties -> smallest i)
            int idx = 31;
            idx = (v30 == m) ? 30 : idx;  idx = (v29 == m) ? 29 : idx;
            idx = (v28 == m) ? 28 : idx;  idx = (v27 == m) ? 27 : idx;
            idx = (v26 == m) ? 26 : idx;  idx = (v25 == m) ? 25 : idx;
            idx = (v24 == m) ? 24 : idx;  idx = (v23 == m) ? 23 : idx;
            idx = (v22 == m) ? 22 : idx;  idx = (v21 == m) ? 21 : idx;
            idx = (v20 == m) ? 20 : idx;  idx = (v19 == m) ? 19 : idx;
            idx = (v18 == m) ? 18 : idx;  idx = (v17 == m) ? 17 : idx;
            idx = (v16 == m) ? 16 : idx;  idx = (v15 == m) ? 15 : idx;
            idx = (v14 == m) ? 14 : idx;  idx = (v13 == m) ? 13 : idx;
            idx = (v12 == m) ? 12 : idx;  idx = (v11 == m) ? 11 : idx;
            idx = (v10 == m) ? 10 : idx;  idx = (v9  == m) ? 9  : idx;
            idx = (v8  == m) ? 8  : idx;  idx = (v7  == m) ? 7  : idx;
            idx = (v6  == m) ? 6  : idx;  idx = (v5  == m) ? 5  : idx;
            idx = (v4  == m) ? 4  : idx;  idx = (v3  == m) ? 3  : idx;
            idx = (v2  == m) ? 2  : idx;  idx = (v1  == m) ? 1  : idx;
            idx = (v0  == m) ? 0  : idx;
            bpb[(size_t)rr * 32 + c] = (unsigned char)idx;
        }
    }
}

// ---------------------------------------------------------------------------
// Kernel 2c: finals + segmented backtrace (verbatim R5). 64 blocks x 1 wave.
// ---------------------------------------------------------------------------
__global__ __launch_bounds__(64) void k_trace(
    const unsigned char* __restrict__ bpg, const float* __restrict__ states,
    const float* __restrict__ en, float* __restrict__ out)
{
    __shared__ __align__(16) unsigned char sbp[511 * 32];  // 16 KB
    __shared__ unsigned char smap[16 * 32];
    const int b = blockIdx.x;
    const int lane = threadIdx.x;
    const int jc = (lane < NK) ? lane : NK - 1;

    {   // stage bp (16352 B = 1022 uint4), coalesced
        const uint4* src = (const uint4*)(bpg + (size_t)b * 511 * 32);
        uint4* dst = (uint4*)sbp;
        for (int i = lane; i < 1022; i += 64) dst[i] = src[i];
    }
    __syncthreads();

    const float* fin = states + (size_t)b * NT * 32 + 511 * 32;
    int li = (lane < 32) ? lane : 0;
    float sv = fin[li];
    float vfin = (lane < NK) ? (sv + en[jc]) : NEG_BIG;
    float M = vfin;
#pragma unroll
    for (int s = 32; s; s >>= 1) M = fmaxf(M, __shfl_xor(M, s));
    unsigned long long mk = __ballot((lane < NK) && vfin == M);
    int last = (int)__builtin_ctzll(mk);

    const int cl = lane & 31;
    const int h = lane >> 5;
    int cur8[8];
#pragma unroll
    for (int rep = 0; rep < 8; ++rep) cur8[rep] = cl;
    for (int off = 0; off < 32; ++off) {
#pragma unroll
        for (int rep = 0; rep < 8; ++rep) {
            int s = 2 * rep + h;
            int hi = (s == 15) ? 511 : 32 * s + 32;
            int r = hi - 1 - off;
            if (r >= 32 * s) cur8[rep] = sbp[r * 32 + cur8[rep]];
        }
    }
#pragma unroll
    for (int rep = 0; rep < 8; ++rep)
        smap[(2 * rep + h) * 32 + cl] = (unsigned char)cur8[rep];

    int myhi = 0, cur = last;
    for (int s = 15; s >= 0; --s) {
        if (lane == s) myhi = cur;
        cur = smap[s * 32 + cur];
    }
    float* op = out + 1 + (size_t)b * NT;
    if (lane == 16) op[NT - 1] = (float)last;
    if (lane < 16) {
        int s = lane;
        int hi = (s == 15) ? 511 : 32 * s + 32;
        int cc = myhi;
        for (int r = hi - 1; r >= 32 * s; --r) {
            cc = sbp[r * 32 + cc];
            op[r] = (float)cc;
        }
    }
}

// ---------------------------------------------------------------------------
// Kernel 3: nll = sum_b (logZ_b - num_b)
// ---------------------------------------------------------------------------
__global__ __launch_bounds__(64) void k_finish(const float* __restrict__ part,
                                               float* __restrict__ out)
{
    float v = part[threadIdx.x];
#pragma unroll
    for (int s = 32; s; s >>= 1) v += __shfl_xor(v, s);
    if (threadIdx.x == 0) out[0] = v;
}

extern "C" void kernel_launch(void* const* d_in, const int* in_sizes, int n_in,
                              void* d_out, int out_size, void* d_ws, size_t ws_size,
                              hipStream_t stream) {
    const int*   x    = (const int*)d_in[0];
    const int*   tags = (const int*)d_in[1];
    const float* emb  = (const float*)d_in[2];
    const float* w    = (const float*)d_in[3];
    const float* bias = (const float*)d_in[4];
    const float* st   = (const float*)d_in[5];
    const float* en   = (const float*)d_in[6];
    const float* tr   = (const float*)d_in[7];
    float* out = (float*)d_out;

    short* wbf    = (short*)d_ws;                            // 48 KB
    float* part   = (float*)((char*)d_ws + 49152);           // 256 B
    float* em     = (float*)((char*)d_ws + 65536);           // 3.80 MB
    float* states = (float*)((char*)d_ws + 3932160);         // 4.19 MB (ws ~8.2 MB)
    // bp aliases em: em is dead after k_scan completes (stream-ordered)
    unsigned char* bp = (unsigned char*)((char*)d_ws + 65536);

    k_prep<<<96, 256, 0, stream>>>(w, wbf);
    k_emissions<<<2048, 128, 0, stream>>>(x, emb, wbf, bias, em);
    k_scan<<<2 * NB, 64, 0, stream>>>(em, tags, st, en, tr, part, states);
    k_bp<<<8 * NB, 64, 0, stream>>>(states, tr, bp);
    k_trace<<<NB, 64, 0, stream>>>(bp, states, en, out);
    k_finish<<<1, 64, 0, stream>>>(part, out);
}

// Round 10
// 288.175 us; speedup vs baseline: 2.6264x; 1.0924x over previous
//
#include <hip/hip_runtime.h>
#include <math.h>

#define NB 64
#define NT 512
#define ND 768
#define NK 29
#define L2E 1.4426950408889634f
#define LN2 0.6931471805599453f
#define NEG_BIG -1e30f

typedef __attribute__((ext_vector_type(8))) short short8;
typedef __attribute__((ext_vector_type(4))) float floatx4;
typedef __attribute__((ext_vector_type(2))) unsigned u32x2;

__device__ __forceinline__ short bf16r(float f) {   // round-to-nearest-even
    unsigned u = __float_as_uint(f);
    unsigned r = (u + 0x7FFFu + ((u >> 16) & 1u)) >> 16;
    return (short)r;
}

// permlane32_swap(x,x): per lane returns {own, partner} (partner = lane^32,
// column-matched) in unspecified slot order. Callers combine ONLY with
// commutative ops (fadd/fmax) -> result independent of slot order, bitwise.
__device__ __forceinline__ void swap32f(float x, float& a, float& b) {
    u32x2 r = __builtin_amdgcn_permlane32_swap(__float_as_uint(x),
                                               __float_as_uint(x), false, false);
    a = __uint_as_float(r[0]);
    b = __uint_as_float(r[1]);
}

// ---------------------------------------------------------------------------
// Kernel 0: convert w (29x768 fp32) -> wbf (32x768 bf16, rows 29..31 zero)
// ---------------------------------------------------------------------------
__global__ __launch_bounds__(256) void k_prep(const float* __restrict__ w,
                                              short* __restrict__ wbf)
{
    int i = blockIdx.x * 256 + threadIdx.x;            // 32*768 = 24576
    if (i < 32 * ND) {
        int row = i / ND;
        wbf[i] = (row < NK) ? bf16r(w[i]) : (short)0;
    }
}

// ---------------------------------------------------------------------------
// Kernel 1: emissions via bf16 MFMA (bitwise-proven; unchanged).
// ---------------------------------------------------------------------------
__global__ __launch_bounds__(128, 2) void k_emissions(
    const int* __restrict__ x, const float* __restrict__ emb,
    const short* __restrict__ wbf, const float* __restrict__ bias,
    float* __restrict__ em)
{
    __shared__ float red[2 * 256];                     // wave1 partials
    const int lane = threadIdx.x & 63;
    const int wv = threadIdx.x >> 6;                   // d-half (0/1)
    const int col = lane & 15;                         // m for A, n for B
    const int quad = lane >> 4;                        // k-subrange selector
    const int Mbase = blockIdx.x * 16;
    const int tok = Mbase + col;

    const float* arow = emb + (size_t)x[tok] * ND + wv * 384 + quad * 8;
    const short* brow0 = wbf + (size_t)col * ND + wv * 384 + quad * 8;
    const short* brow1 = brow0 + 16 * ND;

    // issue ALL A loads first: 24 x global_load_dwordx4 in flight
    float4 a[24];
#pragma unroll
    for (int c = 0; c < 12; ++c) {
        a[2 * c]     = *(const float4*)(arow + c * 32);
        a[2 * c + 1] = *(const float4*)(arow + c * 32 + 4);
    }

    floatx4 acc0 = {0.f, 0.f, 0.f, 0.f};
    floatx4 acc1 = {0.f, 0.f, 0.f, 0.f};

    short8 b0 = *(const short8*)(brow0);               // B is L2-hot (45 KB)
    short8 b1 = *(const short8*)(brow1);

#pragma unroll
    for (int c = 0; c < 12; ++c) {
        int c1 = (c + 1 <= 11) ? c + 1 : 11;           // clamped prefetch
        short8 nb0 = *(const short8*)(brow0 + c1 * 32);
        short8 nb1 = *(const short8*)(brow1 + c1 * 32);

        short8 af;
        af[0] = bf16r(a[2 * c].x);     af[1] = bf16r(a[2 * c].y);
        af[2] = bf16r(a[2 * c].z);     af[3] = bf16r(a[2 * c].w);
        af[4] = bf16r(a[2 * c + 1].x); af[5] = bf16r(a[2 * c + 1].y);
        af[6] = bf16r(a[2 * c + 1].z); af[7] = bf16r(a[2 * c + 1].w);

        acc0 = __builtin_amdgcn_mfma_f32_16x16x32_bf16(af, b0, acc0, 0, 0, 0);
        acc1 = __builtin_amdgcn_mfma_f32_16x16x32_bf16(af, b1, acc1, 0, 0, 0);

        b0 = nb0; b1 = nb1;
    }

    // reduce the two d-halves; C/D layout: row = quad*4+reg, col = lane&15
    const int r0 = quad * 4;
    if (wv == 1) {
#pragma unroll
        for (int reg = 0; reg < 4; ++reg) {
            red[(r0 + reg) * 16 + col]       = acc0[reg];
            red[256 + (r0 + reg) * 16 + col] = acc1[reg];
        }
    }
    __syncthreads();
    if (wv == 0) {
        float bs0 = bias[col];
        float bs1 = (col < NK - 16) ? bias[16 + col] : 0.f;
#pragma unroll
        for (int reg = 0; reg < 4; ++reg) {
            int row = r0 + reg;
            float v0 = acc0[reg] + red[row * 16 + col] + bs0;
            em[(size_t)(Mbase + row) * NK + col] = v0;
            if (col < NK - 16) {
                float v1 = acc1[reg] + red[256 + row * 16 + col] + bs1;
                em[(size_t)(Mbase + row) * NK + 16 + col] = v1;
            }
        }
    }
}

// ---------------------------------------------------------------------------
// Kernel 2: serial scans, LANE-HALF SIMD SPLIT (bitwise-safe).
// CRF: half A (lanes 0-31, col c) runs R0's exact p0,p1 fmaf chains; half B
//   (lanes 32+c, SAME col) runs R0's exact p2,p3 chains. permlane32_swap
//   exchanges (p0+p1)<->(p2+p3) column-matched; final r0+r1 is a commutative
//   fadd == R0's (p0+p1)+(p2+p3) bitwise. Pads contribute fmaf(0,0,p)=p.
// Viterbi (values-only): each half maxes its 16 candidates (exact tree),
//   fmax(r0,r1) combine (exact, commutative) -> state bitwise == R5's, so
//   k_post's recomputed bp/decode are bitwise identical.
// Both: per-step instruction stream nearly halved; ds_reads halved.
// ---------------------------------------------------------------------------
__global__ __launch_bounds__(64) void k_scan(
    const float* __restrict__ em, const int* __restrict__ tags,
    const float* __restrict__ st, const float* __restrict__ en,
    const float* __restrict__ tr, float* __restrict__ part,
    float* __restrict__ states)
{
    __shared__ __align__(16) float sA[32];
    __shared__ __align__(16) unsigned char smem[NT * NK * 4];
    const int lane = threadIdx.x;
    const int c = lane & 31;                           // column owned
    const int h = lane >> 5;                           // chain-half
    const int jc = (c < NK) ? c : NK - 1;

    if (blockIdx.x < NB) {
        // ----------------- CRF forward (R0 chains, split p01/p23) ----------
        const int b = blockIdx.x;
        float* emS = (float*)smem;                     // [512][29]
        {
            const float4* src = (const float4*)(em + (size_t)b * NT * NK);
            float4* dst = (float4*)emS;
            for (int i = lane; i < NT * NK / 4; i += 64) dst[i] = src[i];
        }
        // half A: rows {4ii+0,4ii+1} (p0,p1); half B: rows {4ii+2,4ii+3}
        float EC0[8], EC1[8];
#pragma unroll
        for (int ii = 0; ii < 8; ++ii) {
            int i0 = 4 * ii + 2 * h, i1 = i0 + 1;
            EC0[ii] = (i0 < NK) ? __expf(tr[i0 * NK + jc]) : 0.f;
            EC1[ii] = (i1 < NK) ? __expf(tr[i1 * NK + jc]) : 0.f;
        }
        const float2* sA2 = (const float2*)sA;

        float a0v = __expf(st[jc] + emS[jc]);
        if (lane < 32) sA[lane] = (lane < NK) ? a0v : 0.f;

        int eshift = 5 * (NT - 1);
        float eemc = exp2f(fmaf(emS[NK + jc], L2E, -5.0f));
        float rawn = emS[2 * NK + jc];
        float anew = a0v;

        for (int t = 1; t < NT; ++t) {
            float2 q[8];
#pragma unroll
            for (int ii = 0; ii < 8; ++ii) q[ii] = sA2[2 * ii + h]; // broadcast
            float ph0 = 0.f, ph1 = 0.f;
#pragma unroll
            for (int ii = 0; ii < 8; ++ii) {           // R0's exact chains
                ph0 = fmaf(q[ii].x, EC0[ii], ph0);
                ph1 = fmaf(q[ii].y, EC1[ii], ph1);
            }
            float s = ph0 + ph1;                       // (p0+p1) / (p2+p3)
            float r0, r1;
            swap32f(s, r0, r1);
            anew = (r0 + r1) * eemc;                   // commutative == R0
            // refill (off critical chain)
            eemc = exp2f(fmaf(rawn, L2E, -5.0f));
            int tn = t + 2; tn = tn < NT ? tn : NT - 1;
            rawn = emS[tn * NK + jc];

            if ((t & 15) == 0) {       // exact pow2 renorm via lane-0 probe
                unsigned mb = (unsigned)__builtin_amdgcn_readfirstlane(
                                  __float_as_int(anew));
                int ex = (int)((mb >> 23) & 255u) - 127;
                anew *= __int_as_float((unsigned)(127 - ex) << 23);
                eshift += ex;
            }
            if (lane < 32) sA[lane] = (lane < NK) ? anew : 0.f;
        }
        float val = (lane < NK) ? anew * __expf(en[jc]) : 0.f;
#pragma unroll
        for (int s = 32; s; s >>= 1) val += __shfl_xor(val, s);
        float logZ = logf(val) + (float)eshift * LN2;
        const int* tg = tags + b * NT;
        float p = 0.f;
        for (int t = lane; t < NT; t += 64) {
            int tt = tg[t];
            p += emS[t * NK + tt];
            if (t == 0) p += st[tt];
            else        p += tr[tg[t - 1] * NK + tt];
            if (t == NT - 1) p += en[tt];
        }
#pragma unroll
        for (int s = 32; s; s >>= 1) p += __shfl_xor(p, s);
        if (lane == 0) part[b] = logZ - p;
    } else {
        // ------------- Viterbi forward, values-only, half-split ------------
        const int b = blockIdx.x - NB;
        const float* emb_b = em + (size_t)b * NT * NK;
        float* stt = states + (size_t)b * NT * 32;     // padded rows

        float Tch[16];                                 // rows [16h,16h+16)
#pragma unroll
        for (int r = 0; r < 16; ++r) {
            int i = 16 * h + r;
            Tch[r] = (i < NK) ? tr[i * NK + jc] : 0.f;
        }
        const float4* sAh4 = (const float4*)(sA + 16 * h);

        float sc = (lane < NK) ? (st[jc] + emb_b[jc]) : NEG_BIG;
        if (lane < 32) { sA[lane] = sc; stt[lane] = sc; } // rows 29..31 NEG_BIG

        float e0 = emb_b[1 * NK + jc];
        float e1 = emb_b[2 * NK + jc];
        float e2 = emb_b[3 * NK + jc];
        float e3 = emb_b[4 * NK + jc];

        auto vstep = [&](int t, float emt) {
            float4 q0 = sAh4[0], q1 = sAh4[1], q2 = sAh4[2], q3 = sAh4[3];
            float v0  = q0.x + Tch[0],  v1  = q0.y + Tch[1];
            float v2  = q0.z + Tch[2],  v3  = q0.w + Tch[3];
            float v4  = q1.x + Tch[4],  v5  = q1.y + Tch[5];
            float v6  = q1.z + Tch[6],  v7  = q1.w + Tch[7];
            float v8  = q2.x + Tch[8],  v9  = q2.y + Tch[9];
            float v10 = q2.z + Tch[10], v11 = q2.w + Tch[11];
            float v12 = q3.x + Tch[12], v13 = q3.y + Tch[13];
            float v14 = q3.z + Tch[14], v15 = q3.w + Tch[15];
            float m0 = fmaxf(v0, v1),   m1 = fmaxf(v2, v3);
            float m2 = fmaxf(v4, v5),   m3 = fmaxf(v6, v7);
            float m4 = fmaxf(v8, v9),   m5 = fmaxf(v10, v11);
            float m6 = fmaxf(v12, v13), m7 = fmaxf(v14, v15);
            float n0 = fmaxf(m0, m1), n1 = fmaxf(m2, m3);
            float n2 = fmaxf(m4, m5), n3 = fmaxf(m6, m7);
            float mh = fmaxf(fmaxf(n0, n1), fmaxf(n2, n3)); // half max (exact)
            float r0, r1;
            swap32f(mh, r0, r1);
            float m = fmaxf(r0, r1);                   // exact global max
            sc = (lane < NK) ? (m + emt) : NEG_BIG;
            if (lane < 32) { sA[lane] = sc; stt[t * 32 + lane] = sc; }
        };

        int t = 1;
        for (; t + 3 < NT; t += 4) {
            vstep(t + 0, e0); { int tn = t + 4; tn = tn < NT ? tn : NT - 1; e0 = emb_b[tn * NK + jc]; }
            vstep(t + 1, e1); { int tn = t + 5; tn = tn < NT ? tn : NT - 1; e1 = emb_b[tn * NK + jc]; }
            vstep(t + 2, e2); { int tn = t + 6; tn = tn < NT ? tn : NT - 1; e2 = emb_b[tn * NK + jc]; }
            vstep(t + 3, e3); { int tn = t + 7; tn = tn < NT ? tn : NT - 1; e3 = emb_b[tn * NK + jc]; }
        }
        vstep(509, e0); vstep(510, e1); vstep(511, e2);
        // finals + backtrace in k_post
    }
}

// ---------------------------------------------------------------------------
// Kernel 2b: fused bp + trace + finish. 64 blocks x 512 thr, (512,1) so the
// straight-line body never hits a VGPR cap. Stage all 512 state rows to LDS
// (64 KB), 16 half-waves recompute bp (R9-verbatim straight-line first-max:
// exact value tree + descending priority select == np.argmax), barrier,
// wave 0 runs the R9-verbatim segmented backtrace; block 0 wave 1 sums part[]
// into out[0]. Deletes k_bp/k_trace/k_finish launches + bp global traffic.
// ---------------------------------------------------------------------------
__global__ __launch_bounds__(512, 1) void k_post(
    const float* __restrict__ states, const float* __restrict__ tr,
    const float* __restrict__ en, const float* __restrict__ part,
    float* __restrict__ out)
{
    __shared__ __align__(16) float stt[NT * 32];           // 64 KB
    __shared__ __align__(16) unsigned char sbp[511 * 32];  // 16 KB
    __shared__ unsigned char smap[16 * 32];
    const int b = blockIdx.x;
    const int tid = threadIdx.x;
    const int c = tid & 31;
    const int w = tid >> 5;                                // half-wave 0..15
    const int jc = (c < NK) ? c : NK - 1;

    {   // stage all 512 state rows (4096 float4), coalesced
        const float4* src = (const float4*)(states + (size_t)b * NT * 32);
        float4* dst = (float4*)stt;
#pragma unroll
        for (int i = 0; i < 8; ++i) dst[tid + 512 * i] = src[tid + 512 * i];
    }

    float Tc[32];                                          // static idx only
#pragma unroll
    for (int i = 0; i < NK; ++i) Tc[i] = tr[i * NK + jc];
#pragma unroll
    for (int i = NK; i < 32; ++i) Tc[i] = 0.f;

    __syncthreads();

#pragma unroll 1
    for (int k = 0; k < 32; ++k) {
        int rr = 32 * w + k;                               // bp row rr
        if (rr <= 510) {
            const float4* row = (const float4*)(stt + rr * 32);
            float4 q0 = row[0], q1 = row[1], q2 = row[2], q3 = row[3];
            float4 q4 = row[4], q5 = row[5], q6 = row[6], q7 = row[7];
            float v0  = q0.x + Tc[0],  v1  = q0.y + Tc[1];
            float v2  = q0.z + Tc[2],  v3  = q0.w + Tc[3];
            float v4  = q1.x + Tc[4],  v5  = q1.y + Tc[5];
            float v6  = q1.z + Tc[6],  v7  = q1.w + Tc[7];
            float v8  = q2.x + Tc[8],  v9  = q2.y + Tc[9];
            float v10 = q2.z + Tc[10], v11 = q2.w + Tc[11];
            float v12 = q3.x + Tc[12], v13 = q3.y + Tc[13];
            float v14 = q3.z + Tc[14], v15 = q3.w + Tc[15];
            float v16 = q4.x + Tc[16], v17 = q4.y + Tc[17];
            float v18 = q4.z + Tc[18], v19 = q4.w + Tc[19];
            float v20 = q5.x + Tc[20], v21 = q5.y + Tc[21];
            float v22 = q5.z + Tc[22], v23 = q5.w + Tc[23];
            float v24 = q6.x + Tc[24], v25 = q6.y + Tc[25];
            float v26 = q6.z + Tc[26], v27 = q6.w + Tc[27];
            float v28 = q7.x + Tc[28], v29 = q7.y + Tc[29];
            float v30 = q7.z + Tc[30], v31 = q7.w + Tc[31];
            float m0 = fmaxf(v0, v1),   m1 = fmaxf(v2, v3);
            float m2 = fmaxf(v4, v5),   m3 = fmaxf(v6, v7);
            float m4 = fmaxf(v8, v9),   m5 = fmaxf(v10, v11);
            float m6 = fmaxf(v12, v13), m7 = fmaxf(v14, v15);
            float m8 = fmaxf(v16, v17), m9 = fmaxf(v18, v19);
            float ma = fmaxf(v20, v21), mb = fmaxf(v22, v23);
            float mc = fmaxf(v24, v25), md = fmaxf(v26, v27);
            float me = fmaxf(v28, v29), mf = fmaxf(v30, v31);
            float n0 = fmaxf(m0, m1), n1 = fmaxf(m2, m3);
            float n2 = fmaxf(m4, m5), n3 = fmaxf(m6, m7);
            float n4 = fmaxf(m8, m9), n5 = fmaxf(ma, mb);
            float n6 = fmaxf(mc, md), n7 = fmaxf(me, mf);
            float o0 = fmaxf(n0, n1), o1 = fmaxf(n2, n3);
            float o2 = fmaxf(n4, n5), o3 = fmaxf(n6, n7);
            float m  = fmaxf(fmaxf(o0, o1), fmaxf(o2, o3));
            int idx = 31;
            idx = (v30 == m) ? 30 : idx;  idx = (v29 == m) ? 29 : idx;
            idx = (v28 == m) ? 28 : idx;  idx = (v27 == m) ? 27 : idx;
            idx = (v26 == m) ? 26 : idx;  idx = (v25 == m) ? 25 : idx;
            idx = (v24 == m) ? 24 : idx;  idx = (v23 == m) ? 23 : idx;
            idx = (v22 == m) ? 22 : idx;  idx = (v21 == m) ? 21 : idx;
            idx = (v20 == m) ? 20 : idx;  idx = (v19 == m) ? 19 : idx;
            idx = (v18 == m) ? 18 : idx;  idx = (v17 == m) ? 17 : idx;
            idx = (v16 == m) ? 16 : idx;  idx = (v15 == m) ? 15 : idx;
            idx = (v14 == m) ? 14 : idx;  idx = (v13 == m) ? 13 : idx;
            idx = (v12 == m) ? 12 : idx;  idx = (v11 == m) ? 11 : idx;
            idx = (v10 == m) ? 10 : idx;  idx = (v9  == m) ? 9  : idx;
            idx = (v8  == m) ? 8  : idx;  idx = (v7  == m) ? 7  : idx;
            idx = (v6  == m) ? 6  : idx;  idx = (v5  == m) ? 5  : idx;
            idx = (v4  == m) ? 4  : idx;  idx = (v3  == m) ? 3  : idx;
            idx = (v2  == m) ? 2  : idx;  idx = (v1  == m) ? 1  : idx;
            idx = (v0  == m) ? 0  : idx;
            sbp[rr * 32 + c] = (unsigned char)idx;
        }
    }
    __syncthreads();

    if (tid < 64) {    // wave 0: finals + segmented backtrace (verbatim)
        const int lane = tid;
        float sv = stt[511 * 32 + ((lane < 32) ? lane : 0)];
        float vfin = (lane < NK) ? (sv + en[jc]) : NEG_BIG;
        float M = vfin;
#pragma unroll
        for (int s = 32; s; s >>= 1) M = fmaxf(M, __shfl_xor(M, s));
        unsigned long long mk = __ballot((lane < NK) && vfin == M);
        int last = (int)__builtin_ctzll(mk);

        const int cl = lane & 31;
        const int hh = lane >> 5;
        int cur8[8];
#pragma unroll
        for (int rep = 0; rep < 8; ++rep) cur8[rep] = cl;
        for (int off = 0; off < 32; ++off) {
#pragma unroll
            for (int rep = 0; rep < 8; ++rep) {
                int s = 2 * rep + hh;
                int hi = (s == 15) ? 511 : 32 * s + 32;
                int r = hi - 1 - off;
                if (r >= 32 * s) cur8[rep] = sbp[r * 32 + cur8[rep]];
            }
        }
#pragma unroll
        for (int rep = 0; rep < 8; ++rep)
            smap[(2 * rep + hh) * 32 + cl] = (unsigned char)cur8[rep];

        int myhi = 0, cur = last;
        for (int s = 15; s >= 0; --s) {
            if (lane == s) myhi = cur;
            cur = smap[s * 32 + cur];
        }
        float* op = out + 1 + (size_t)b * NT;
        if (lane == 16) op[NT - 1] = (float)last;
        if (lane < 16) {
            int s = lane;
            int hi = (s == 15) ? 511 : 32 * s + 32;
            int cc = myhi;
            for (int r = hi - 1; r >= 32 * s; --r) {
                cc = sbp[r * 32 + cc];
                op[r] = (float)cc;
            }
        }
    } else if (b == 0 && tid < 128) {   // block 0, wave 1: nll reduction
        int l2 = tid - 64;
        float v = part[l2];
#pragma unroll
        for (int s = 32; s; s >>= 1) v += __shfl_xor(v, s);
        if (l2 == 0) out[0] = v;
    }
}

extern "C" void kernel_launch(void* const* d_in, const int* in_sizes, int n_in,
                              void* d_out, int out_size, void* d_ws, size_t ws_size,
                              hipStream_t stream) {
    const int*   x    = (const int*)d_in[0];
    const int*   tags = (const int*)d_in[1];
    const float* emb  = (const float*)d_in[2];
    const float* w    = (const float*)d_in[3];
    const float* bias = (const float*)d_in[4];
    const float* st   = (const float*)d_in[5];
    const float* en   = (const float*)d_in[6];
    const float* tr   = (const float*)d_in[7];
    float* out = (float*)d_out;

    short* wbf    = (short*)d_ws;                            // 48 KB
    float* part   = (float*)((char*)d_ws + 49152);           // 256 B
    float* em     = (float*)((char*)d_ws + 65536);           // 3.80 MB
    float* states = (float*)((char*)d_ws + 3932160);         // 4.19 MB (ws ~8.2 MB)

    k_prep<<<96, 256, 0, stream>>>(w, wbf);
    k_emissions<<<2048, 128, 0, stream>>>(x, emb, wbf, bias, em);
    k_scan<<<2 * NB, 64, 0, stream>>>(em, tags, st, en, tr, part, states);
    k_post<<<NB, 512, 0, stream>>>(states, tr, en, part, out);
}